// Round 1
// baseline (648.509 us; speedup 1.0000x reference)
//
#include <hip/hip_runtime.h>
#include <math.h>

// MP_Attention: B=4,S=4096,E=1024,H=16,hd=64
// Pipeline: prep_w -> cvt_x -> gemm_qkv(+qk head-norm epilogue) -> scores(partial)
//           -> softmax(reduce partials) -> pv -> gemm_out(+residual mix)
// Workspace layout (bytes):
//   WN   [3072x1024] bf16 @ 0          (6,291,456)
//   WNO  [1024x1024] bf16 @ 6291456    (2,097,152)
//   xb   [16384x1024] bf16 @ 8388608   (33,554,432)   (reused as `o` after gemm_qkv)
//   qkv  [16384x3072] bf16 @ 41943040  (100,663,296)
//   part [64][64][64][64] f32 @ 142606336 (67,108,864)
//   attn [64][64][64] bf16 @ 209715200 (524,288)
// total ~210.2 MB

typedef __bf16 bf16;
typedef __bf16 bf16x8 __attribute__((ext_vector_type(8)));
typedef __bf16 bf16x4 __attribute__((ext_vector_type(4)));
typedef float  f32x4  __attribute__((ext_vector_type(4)));

#define DEVINL __device__ __forceinline__

DEVINL void gload_lds16(const void* g, void* l) {
  __builtin_amdgcn_global_load_lds(
      (__attribute__((address_space(1))) void*)(void*)g,
      (__attribute__((address_space(3))) void*)l, 16, 0, 0);
}

static constexpr int Sq = 4096;
static constexpr int Ek = 1024;
static constexpr int Mrows = 16384;   // B*S

// ---------------- weight prep: mp_normalize rows + gain/sqrt(fan_in), f32->bf16 ----
__global__ __launch_bounds__(256) void k_prep_w(
    const float* __restrict__ wq, const float* __restrict__ wk,
    const float* __restrict__ wv, const float* __restrict__ wo,
    const float* __restrict__ gain_p,
    bf16* __restrict__ WN, bf16* __restrict__ WNO) {
  int r = blockIdx.x;            // 0..4095
  int mat = r >> 10, row = r & 1023;
  const float* w = (mat == 0) ? wq : (mat == 1) ? wk : (mat == 2) ? wv : wo;
  int t = threadIdx.x;
  f32x4 v = *(const f32x4*)&w[(size_t)row * 1024 + t * 4];
  float ss = v[0]*v[0] + v[1]*v[1] + v[2]*v[2] + v[3]*v[3];
#pragma unroll
  for (int m2 = 1; m2 < 64; m2 <<= 1) ss += __shfl_xor(ss, m2);
  __shared__ float red[4];
  if ((t & 63) == 0) red[t >> 6] = ss;
  __syncthreads();
  float tot = red[0] + red[1] + red[2] + red[3];
  float g = gain_p[0];
  // wn = w / (eps + ||w||/32) * gain/32
  float scale = (g * 0.03125f) / (1e-4f + sqrtf(tot) * 0.03125f);
  bf16x4 ov;
  ov[0] = (bf16)(v[0]*scale); ov[1] = (bf16)(v[1]*scale);
  ov[2] = (bf16)(v[2]*scale); ov[3] = (bf16)(v[3]*scale);
  if (mat < 3) *(bf16x4*)&WN [(size_t)r   * 1024 + t * 4] = ov;
  else         *(bf16x4*)&WNO[(size_t)row * 1024 + t * 4] = ov;
}

// ---------------- x f32 -> bf16 -------------------------------------------------
__global__ __launch_bounds__(256) void k_cvt_x(const float* __restrict__ x,
                                               bf16* __restrict__ xb) {
  size_t idx = (size_t)blockIdx.x * 256 + threadIdx.x;
  const size_t n8 = (size_t)Mrows * Ek / 8;
  for (size_t i = idx; i < n8; i += (size_t)2048 * 256) {
    f32x4 a = *(const f32x4*)&x[i * 8];
    f32x4 b = *(const f32x4*)&x[i * 8 + 4];
    bf16x8 ov;
    ov[0]=(bf16)a[0]; ov[1]=(bf16)a[1]; ov[2]=(bf16)a[2]; ov[3]=(bf16)a[3];
    ov[4]=(bf16)b[0]; ov[5]=(bf16)b[1]; ov[6]=(bf16)b[2]; ov[7]=(bf16)b[3];
    *(bf16x8*)&xb[i * 8] = ov;
  }
}

// ---------------- GEMM: C[M x N] = A[M x 1024] * Bw[N x 1024]^T  (m97 structure) --
// EPI=0: store bf16, per-(row,64col-group) mp_normalize for cols<2048 (q,k)
// EPI=1: store f32 = (resid + acc) * 0.7071067811
template <int EPI>
__global__ __launch_bounds__(256) void k_gemm(const bf16* __restrict__ A,
                                              const bf16* __restrict__ Bw,
                                              void* __restrict__ Cout,
                                              const float* __restrict__ resid,
                                              int N) {
  constexpr int K = 1024;
  __shared__ bf16 As[128 * 32];
  __shared__ bf16 Bs[128 * 32];
  int m0 = blockIdx.y * 128, n0 = blockIdx.x * 128;
  int t = threadIdx.x, lane = t & 63, w = t >> 6;
  int wr = w >> 1, wc = w & 1;
  f32x4 acc[4][4] = {};

  const bf16* aptr0 = A  + (size_t)(m0 + (t >> 2)) * K + (t & 3) * 8;
  const bf16* bptr0 = Bw + (size_t)(n0 + (t >> 2)) * K + (t & 3) * 8;

  for (int kt = 0; kt < K / 32; ++kt) {
    __syncthreads();                      // previous tile fully consumed
    const bf16* ag = aptr0 + kt * 32;
    const bf16* bg = bptr0 + kt * 32;
    gload_lds16(ag,            &As[t * 8]);
    gload_lds16(ag + 64 * K,   &As[2048 + t * 8]);
    gload_lds16(bg,            &Bs[t * 8]);
    gload_lds16(bg + 64 * K,   &Bs[2048 + t * 8]);
    __syncthreads();                      // vmcnt(0) drain + barrier

    bf16x8 af[4], bfr[4];
    int kof = (lane >> 4) * 8;
    int arow = wr * 64 + (lane & 15);
    int brow = wc * 64 + (lane & 15);
#pragma unroll
    for (int mi = 0; mi < 4; ++mi) af[mi]  = *(const bf16x8*)&As[(arow + mi * 16) * 32 + kof];
#pragma unroll
    for (int ni = 0; ni < 4; ++ni) bfr[ni] = *(const bf16x8*)&Bs[(brow + ni * 16) * 32 + kof];
#pragma unroll
    for (int mi = 0; mi < 4; ++mi)
#pragma unroll
      for (int ni = 0; ni < 4; ++ni)
        acc[mi][ni] = __builtin_amdgcn_mfma_f32_16x16x32_bf16(af[mi], bfr[ni], acc[mi][ni], 0, 0, 0);
  }

  int colbase = n0 + wc * 64 + (lane & 15);
  if constexpr (EPI == 0) {
    bf16* C = (bf16*)Cout;
    bool dn = (n0 + wc * 64) < 2048;      // q,k cols get head-norm; v cols don't
#pragma unroll
    for (int mi = 0; mi < 4; ++mi) {
#pragma unroll
      for (int r = 0; r < 4; ++r) {
        float scale = 1.f;
        if (dn) {
          float ss = 0.f;
#pragma unroll
          for (int ni = 0; ni < 4; ++ni) { float v = acc[mi][ni][r]; ss += v * v; }
          ss += __shfl_xor(ss, 1); ss += __shfl_xor(ss, 2);
          ss += __shfl_xor(ss, 4); ss += __shfl_xor(ss, 8);
          scale = 1.f / (1e-4f + sqrtf(ss) * 0.125f);   // eps + ||v||/sqrt(64)
        }
        int row = m0 + wr * 64 + mi * 16 + ((lane >> 4) << 2) + r;
        size_t base = (size_t)row * N + colbase;
#pragma unroll
        for (int ni = 0; ni < 4; ++ni)
          C[base + ni * 16] = (bf16)(acc[mi][ni][r] * scale);
      }
    }
  } else {
    float* C = (float*)Cout;
#pragma unroll
    for (int mi = 0; mi < 4; ++mi) {
#pragma unroll
      for (int r = 0; r < 4; ++r) {
        int row = m0 + wr * 64 + mi * 16 + ((lane >> 4) << 2) + r;
        size_t base = (size_t)row * N + colbase;
#pragma unroll
        for (int ni = 0; ni < 4; ++ni) {
          size_t idx = base + ni * 16;
          C[idx] = (resid[idx] + acc[mi][ni][r]) * 0.70710678118654752f;
        }
      }
    }
  }
}

// ---------------- scores partials: part[p][c][h][k] = sum_{s in chunk} qn*kn -----
__global__ __launch_bounds__(256) void k_scores(const bf16* __restrict__ qkv,
                                                float* __restrict__ part) {
  __shared__ float Qs[64][64];
  __shared__ float Ks[64][64];
  int blk = blockIdx.x;                  // p*64 + c
  int p = blk >> 6, c = blk & 63;
  int b = p >> 4, n = p & 15;
  int t = threadIdx.x;
  int j = t & 7;
  size_t rowbase = ((size_t)(b * 4096 + c * 64)) * 3072 + n * 64 + j * 8;
#pragma unroll
  for (int i = 0; i < 2; ++i) {
    int sl = i * 32 + (t >> 3);
    bf16x8 qv = *(const bf16x8*)&qkv[rowbase + (size_t)sl * 3072];
    bf16x8 kv = *(const bf16x8*)&qkv[rowbase + (size_t)sl * 3072 + 1024];
    f32x4 q0, q1, k0v, k1v;
    q0[0]=(float)qv[0]; q0[1]=(float)qv[1]; q0[2]=(float)qv[2]; q0[3]=(float)qv[3];
    q1[0]=(float)qv[4]; q1[1]=(float)qv[5]; q1[2]=(float)qv[6]; q1[3]=(float)qv[7];
    k0v[0]=(float)kv[0]; k0v[1]=(float)kv[1]; k0v[2]=(float)kv[2]; k0v[3]=(float)kv[3];
    k1v[0]=(float)kv[4]; k1v[1]=(float)kv[5]; k1v[2]=(float)kv[6]; k1v[3]=(float)kv[7];
    *(f32x4*)&Qs[sl][j * 8]     = q0;
    *(f32x4*)&Qs[sl][j * 8 + 4] = q1;
    *(f32x4*)&Ks[sl][j * 8]     = k0v;
    *(f32x4*)&Ks[sl][j * 8 + 4] = k1v;
  }
  __syncthreads();
  int h0 = (t >> 4) << 2, k0 = (t & 15) << 2;
  float acc[4][4] = {};
  for (int s = 0; s < 64; ++s) {
    f32x4 q  = *(const f32x4*)&Qs[s][h0];
    f32x4 kk = *(const f32x4*)&Ks[s][k0];
#pragma unroll
    for (int a = 0; a < 4; ++a) {
      acc[a][0] += q[a] * kk[0]; acc[a][1] += q[a] * kk[1];
      acc[a][2] += q[a] * kk[2]; acc[a][3] += q[a] * kk[3];
    }
  }
  size_t base = (size_t)blk * 4096;
#pragma unroll
  for (int a = 0; a < 4; ++a) {
    f32x4 st; st[0]=acc[a][0]; st[1]=acc[a][1]; st[2]=acc[a][2]; st[3]=acc[a][3];
    *(f32x4*)&part[base + (size_t)(h0 + a) * 64 + k0] = st;
  }
}

// ---------------- softmax over k (64) with 1/64 score scale; reduce 64 partials --
__global__ __launch_bounds__(256) void k_softmax(const float* __restrict__ part,
                                                 bf16* __restrict__ attn) {
  int p = blockIdx.x;                    // 0..63
  int t = threadIdx.x, lane = t & 63, w = t >> 6;
  const float* pp = part + (size_t)p * 64 * 4096;
#pragma unroll 1
  for (int i = 0; i < 16; ++i) {
    int h = i * 4 + w;
    float s = 0.f;
    for (int c = 0; c < 64; ++c) s += pp[(size_t)c * 4096 + h * 64 + lane];
    s *= (1.0f / 64.0f);                 // k / sqrt(S)
    float mx = s;
#pragma unroll
    for (int m2 = 1; m2 < 64; m2 <<= 1) mx = fmaxf(mx, __shfl_xor(mx, m2));
    float e = __expf(s - mx);
    float sum = e;
#pragma unroll
    for (int m2 = 1; m2 < 64; m2 <<= 1) sum += __shfl_xor(sum, m2);
    attn[(size_t)p * 4096 + h * 64 + lane] = (bf16)(e / sum);
  }
}

// ---------------- PV: o[s, n*64+h] = sum_k attn[h,k] * v[s,k] --------------------
__global__ __launch_bounds__(256) void k_pv(const bf16* __restrict__ qkv,
                                            const bf16* __restrict__ attn,
                                            bf16* __restrict__ o) {
  int blk = blockIdx.x;                  // p*16 + chunk
  int p = blk >> 4, ch = blk & 15;
  int b = p >> 4, n = p & 15;
  int t = threadIdx.x, lane = t & 63, w = t >> 6;
  int s0 = ch * 256 + w * 64;
  size_t vrow0 = (size_t)(b * 4096 + s0);
  const bf16* At = attn + (size_t)p * 4096;
  f32x4 acc[4][4] = {};
#pragma unroll
  for (int ks = 0; ks < 2; ++ks) {
    int kof = ks * 32 + ((lane >> 4) << 3);
    bf16x8 vf[4], af[4];
#pragma unroll
    for (int mi = 0; mi < 4; ++mi)
      vf[mi] = *(const bf16x8*)&qkv[(vrow0 + mi * 16 + (lane & 15)) * 3072 + 2048 + n * 64 + kof];
#pragma unroll
    for (int ni = 0; ni < 4; ++ni)
      af[ni] = *(const bf16x8*)&At[(size_t)(ni * 16 + (lane & 15)) * 64 + kof];
#pragma unroll
    for (int mi = 0; mi < 4; ++mi)
#pragma unroll
      for (int ni = 0; ni < 4; ++ni)
        acc[mi][ni] = __builtin_amdgcn_mfma_f32_16x16x32_bf16(vf[mi], af[ni], acc[mi][ni], 0, 0, 0);
  }
#pragma unroll
  for (int mi = 0; mi < 4; ++mi)
#pragma unroll
    for (int r = 0; r < 4; ++r) {
      int srow = s0 + mi * 16 + ((lane >> 4) << 2) + r;
      size_t base = ((size_t)(b * 4096 + srow)) * 1024 + n * 64 + (lane & 15);
#pragma unroll
      for (int ni = 0; ni < 4; ++ni)
        o[base + ni * 16] = (bf16)acc[mi][ni][r];
    }
}

// ---------------------------------------------------------------------------------
extern "C" void kernel_launch(void* const* d_in, const int* in_sizes, int n_in,
                              void* d_out, int out_size, void* d_ws, size_t ws_size,
                              hipStream_t stream) {
  const float* x    = (const float*)d_in[0];
  const float* gain = (const float*)d_in[1];
  const float* wq   = (const float*)d_in[2];
  const float* wk   = (const float*)d_in[3];
  const float* wv   = (const float*)d_in[4];
  const float* wo   = (const float*)d_in[5];

  char* ws = (char*)d_ws;
  bf16*  WN   = (bf16*)(ws + 0);
  bf16*  WNO  = (bf16*)(ws + 6291456);
  bf16*  xb   = (bf16*)(ws + 8388608);
  bf16*  qkv  = (bf16*)(ws + 41943040);
  float* part = (float*)(ws + 142606336);
  bf16*  attn = (bf16*)(ws + 209715200);
  bf16*  o    = xb;  // xb dead after gemm_qkv; reuse for o

  k_prep_w<<<4096, 256, 0, stream>>>(wq, wk, wv, wo, gain, WN, WNO);
  k_cvt_x<<<2048, 256, 0, stream>>>(x, xb);
  k_gemm<0><<<dim3(24, 128), 256, 0, stream>>>(xb, WN, (void*)qkv, nullptr, 3072);
  k_scores<<<4096, 256, 0, stream>>>(qkv, part);
  k_softmax<<<64, 256, 0, stream>>>(part, attn);
  k_pv<<<1024, 256, 0, stream>>>(qkv, attn, o);
  k_gemm<1><<<dim3(8, 128), 256, 0, stream>>>(o, WNO, d_out, x, 1024);
}

// Round 2
// 419.517 us; speedup vs baseline: 1.5458x; 1.5458x over previous
//
#include <hip/hip_runtime.h>
#include <math.h>

// MP_Attention: B=4,S=4096,E=1024,H=16,hd=64
// Pipeline: prep_w -> cvt_x -> gemm_qkv(+qk head-norm epilogue) -> scores(partial)
//           -> softmax(reduce partials, parallel) -> pv -> gemm_out(+residual mix)
// Workspace layout (bytes):
//   WN   [3072x1024] bf16 @ 0          (6,291,456)
//   WNO  [1024x1024] bf16 @ 6291456    (2,097,152)
//   xb   [16384x1024] bf16 @ 8388608   (33,554,432)   (reused as `o` after gemm_qkv)
//   qkv  [16384x3072] bf16 @ 41943040  (100,663,296)
//   part [64][64][64][64] f32 @ 142606336 (67,108,864)
//   attn [64][64][64] bf16 @ 209715200 (524,288)
// total ~210.2 MB

typedef __bf16 bf16;
typedef __bf16 bf16x8 __attribute__((ext_vector_type(8)));
typedef __bf16 bf16x4 __attribute__((ext_vector_type(4)));
typedef float  f32x4  __attribute__((ext_vector_type(4)));

#define DEVINL __device__ __forceinline__

DEVINL void gload_lds16(const void* g, void* l) {
  __builtin_amdgcn_global_load_lds(
      (__attribute__((address_space(1))) void*)(void*)g,
      (__attribute__((address_space(3))) void*)l, 16, 0, 0);
}

static constexpr int Sq = 4096;
static constexpr int Ek = 1024;
static constexpr int Mrows = 16384;   // B*S

// ---------------- weight prep: mp_normalize rows + gain/sqrt(fan_in), f32->bf16 ----
__global__ __launch_bounds__(256) void k_prep_w(
    const float* __restrict__ wq, const float* __restrict__ wk,
    const float* __restrict__ wv, const float* __restrict__ wo,
    const float* __restrict__ gain_p,
    bf16* __restrict__ WN, bf16* __restrict__ WNO) {
  int r = blockIdx.x;            // 0..4095
  int mat = r >> 10, row = r & 1023;
  const float* w = (mat == 0) ? wq : (mat == 1) ? wk : (mat == 2) ? wv : wo;
  int t = threadIdx.x;
  f32x4 v = *(const f32x4*)&w[(size_t)row * 1024 + t * 4];
  float ss = v[0]*v[0] + v[1]*v[1] + v[2]*v[2] + v[3]*v[3];
#pragma unroll
  for (int m2 = 1; m2 < 64; m2 <<= 1) ss += __shfl_xor(ss, m2);
  __shared__ float red[4];
  if ((t & 63) == 0) red[t >> 6] = ss;
  __syncthreads();
  float tot = red[0] + red[1] + red[2] + red[3];
  float g = gain_p[0];
  // wn = w / (eps + ||w||/32) * gain/32
  float scale = (g * 0.03125f) / (1e-4f + sqrtf(tot) * 0.03125f);
  bf16x4 ov;
  ov[0] = (bf16)(v[0]*scale); ov[1] = (bf16)(v[1]*scale);
  ov[2] = (bf16)(v[2]*scale); ov[3] = (bf16)(v[3]*scale);
  if (mat < 3) *(bf16x4*)&WN [(size_t)r   * 1024 + t * 4] = ov;
  else         *(bf16x4*)&WNO[(size_t)row * 1024 + t * 4] = ov;
}

// ---------------- x f32 -> bf16 -------------------------------------------------
__global__ __launch_bounds__(256) void k_cvt_x(const float* __restrict__ x,
                                               bf16* __restrict__ xb) {
  size_t idx = (size_t)blockIdx.x * 256 + threadIdx.x;
  const size_t n8 = (size_t)Mrows * Ek / 8;
  for (size_t i = idx; i < n8; i += (size_t)2048 * 256) {
    f32x4 a = *(const f32x4*)&x[i * 8];
    f32x4 b = *(const f32x4*)&x[i * 8 + 4];
    bf16x8 ov;
    ov[0]=(bf16)a[0]; ov[1]=(bf16)a[1]; ov[2]=(bf16)a[2]; ov[3]=(bf16)a[3];
    ov[4]=(bf16)b[0]; ov[5]=(bf16)b[1]; ov[6]=(bf16)b[2]; ov[7]=(bf16)b[3];
    *(bf16x8*)&xb[i * 8] = ov;
  }
}

// ---------------- GEMM: C[M x N] = A[M x 1024] * Bw[N x 1024]^T  (m97 structure) --
// EPI=0: store bf16, per-(row,64col-group) mp_normalize for cols<2048 (q,k)
// EPI=1: store f32 = (resid + acc) * 0.7071067811
template <int EPI>
__global__ __launch_bounds__(256) void k_gemm(const bf16* __restrict__ A,
                                              const bf16* __restrict__ Bw,
                                              void* __restrict__ Cout,
                                              const float* __restrict__ resid,
                                              int N) {
  constexpr int K = 1024;
  __shared__ bf16 As[128 * 32];
  __shared__ bf16 Bs[128 * 32];
  int m0 = blockIdx.y * 128, n0 = blockIdx.x * 128;
  int t = threadIdx.x, lane = t & 63, w = t >> 6;
  int wr = w >> 1, wc = w & 1;
  f32x4 acc[4][4] = {};

  const bf16* aptr0 = A  + (size_t)(m0 + (t >> 2)) * K + (t & 3) * 8;
  const bf16* bptr0 = Bw + (size_t)(n0 + (t >> 2)) * K + (t & 3) * 8;

  for (int kt = 0; kt < K / 32; ++kt) {
    __syncthreads();                      // previous tile fully consumed
    const bf16* ag = aptr0 + kt * 32;
    const bf16* bg = bptr0 + kt * 32;
    gload_lds16(ag,            &As[t * 8]);
    gload_lds16(ag + 64 * K,   &As[2048 + t * 8]);
    gload_lds16(bg,            &Bs[t * 8]);
    gload_lds16(bg + 64 * K,   &Bs[2048 + t * 8]);
    __syncthreads();                      // vmcnt(0) drain + barrier

    bf16x8 af[4], bfr[4];
    int kof = (lane >> 4) * 8;
    int arow = wr * 64 + (lane & 15);
    int brow = wc * 64 + (lane & 15);
#pragma unroll
    for (int mi = 0; mi < 4; ++mi) af[mi]  = *(const bf16x8*)&As[(arow + mi * 16) * 32 + kof];
#pragma unroll
    for (int ni = 0; ni < 4; ++ni) bfr[ni] = *(const bf16x8*)&Bs[(brow + ni * 16) * 32 + kof];
#pragma unroll
    for (int mi = 0; mi < 4; ++mi)
#pragma unroll
      for (int ni = 0; ni < 4; ++ni)
        acc[mi][ni] = __builtin_amdgcn_mfma_f32_16x16x32_bf16(af[mi], bfr[ni], acc[mi][ni], 0, 0, 0);
  }

  int colbase = n0 + wc * 64 + (lane & 15);
  if constexpr (EPI == 0) {
    bf16* C = (bf16*)Cout;
    bool dn = (n0 + wc * 64) < 2048;      // q,k cols get head-norm; v cols don't
#pragma unroll
    for (int mi = 0; mi < 4; ++mi) {
#pragma unroll
      for (int r = 0; r < 4; ++r) {
        float scale = 1.f;
        if (dn) {
          float ss = 0.f;
#pragma unroll
          for (int ni = 0; ni < 4; ++ni) { float v = acc[mi][ni][r]; ss += v * v; }
          ss += __shfl_xor(ss, 1); ss += __shfl_xor(ss, 2);
          ss += __shfl_xor(ss, 4); ss += __shfl_xor(ss, 8);
          scale = 1.f / (1e-4f + sqrtf(ss) * 0.125f);   // eps + ||v||/sqrt(64)
        }
        int row = m0 + wr * 64 + mi * 16 + ((lane >> 4) << 2) + r;
        size_t base = (size_t)row * N + colbase;
#pragma unroll
        for (int ni = 0; ni < 4; ++ni)
          C[base + ni * 16] = (bf16)(acc[mi][ni][r] * scale);
      }
    }
  } else {
    float* C = (float*)Cout;
#pragma unroll
    for (int mi = 0; mi < 4; ++mi) {
#pragma unroll
      for (int r = 0; r < 4; ++r) {
        int row = m0 + wr * 64 + mi * 16 + ((lane >> 4) << 2) + r;
        size_t base = (size_t)row * N + colbase;
#pragma unroll
        for (int ni = 0; ni < 4; ++ni) {
          size_t idx = base + ni * 16;
          C[idx] = (resid[idx] + acc[mi][ni][r]) * 0.70710678118654752f;
        }
      }
    }
  }
}

// ---------------- scores partials: part[p][c][h][k] = sum_{s in chunk} qn*kn -----
__global__ __launch_bounds__(256) void k_scores(const bf16* __restrict__ qkv,
                                                float* __restrict__ part) {
  __shared__ float Qs[64][64];
  __shared__ float Ks[64][64];
  int blk = blockIdx.x;                  // p*64 + c
  int p = blk >> 6, c = blk & 63;
  int b = p >> 4, n = p & 15;
  int t = threadIdx.x;
  int j = t & 7;
  size_t rowbase = ((size_t)(b * 4096 + c * 64)) * 3072 + n * 64 + j * 8;
#pragma unroll
  for (int i = 0; i < 2; ++i) {
    int sl = i * 32 + (t >> 3);
    bf16x8 qv = *(const bf16x8*)&qkv[rowbase + (size_t)sl * 3072];
    bf16x8 kv = *(const bf16x8*)&qkv[rowbase + (size_t)sl * 3072 + 1024];
    f32x4 q0, q1, k0v, k1v;
    q0[0]=(float)qv[0]; q0[1]=(float)qv[1]; q0[2]=(float)qv[2]; q0[3]=(float)qv[3];
    q1[0]=(float)qv[4]; q1[1]=(float)qv[5]; q1[2]=(float)qv[6]; q1[3]=(float)qv[7];
    k0v[0]=(float)kv[0]; k0v[1]=(float)kv[1]; k0v[2]=(float)kv[2]; k0v[3]=(float)kv[3];
    k1v[0]=(float)kv[4]; k1v[1]=(float)kv[5]; k1v[2]=(float)kv[6]; k1v[3]=(float)kv[7];
    *(f32x4*)&Qs[sl][j * 8]     = q0;
    *(f32x4*)&Qs[sl][j * 8 + 4] = q1;
    *(f32x4*)&Ks[sl][j * 8]     = k0v;
    *(f32x4*)&Ks[sl][j * 8 + 4] = k1v;
  }
  __syncthreads();
  int h0 = (t >> 4) << 2, k0 = (t & 15) << 2;
  float acc[4][4] = {};
  for (int s = 0; s < 64; ++s) {
    f32x4 q  = *(const f32x4*)&Qs[s][h0];
    f32x4 kk = *(const f32x4*)&Ks[s][k0];
#pragma unroll
    for (int a = 0; a < 4; ++a) {
      acc[a][0] += q[a] * kk[0]; acc[a][1] += q[a] * kk[1];
      acc[a][2] += q[a] * kk[2]; acc[a][3] += q[a] * kk[3];
    }
  }
  size_t base = (size_t)blk * 4096;
#pragma unroll
  for (int a = 0; a < 4; ++a) {
    f32x4 st; st[0]=acc[a][0]; st[1]=acc[a][1]; st[2]=acc[a][2]; st[3]=acc[a][3];
    *(f32x4*)&part[base + (size_t)(h0 + a) * 64 + k0] = st;
  }
}

// ---------------- reduce partials + softmax over k (64), parallel ----------------
// grid: 256 blocks = 64 pairs x 4 quarters; block owns 1024 consecutive elems of
// scores[p][h*64+k]. Each thread: f32x4 over e0 = q*1024 + t*4 (one h-row spans
// 16 lanes x 4 elems). Reduce 64 chunk-partials (coalesced 4KB/chunk/block),
// then 16-lane shfl softmax.
__global__ __launch_bounds__(256) void k_softmax(const float* __restrict__ part,
                                                 bf16* __restrict__ attn) {
  int blk = blockIdx.x;                  // p*4 + q
  int p = blk >> 2, q = blk & 3;
  int t = threadIdx.x;
  int e0 = q * 1024 + t * 4;
  const float* pp = part + (size_t)p * 64 * 4096 + e0;
  f32x4 s = {};
#pragma unroll 4
  for (int c = 0; c < 64; ++c) {
    f32x4 v = *(const f32x4*)&pp[(size_t)c * 4096];
    s[0] += v[0]; s[1] += v[1]; s[2] += v[2]; s[3] += v[3];
  }
  const float sc = 1.0f / 64.0f;         // k / sqrt(S) folded: 1/sqrt(4096)... (see note)
  s[0] *= sc; s[1] *= sc; s[2] *= sc; s[3] *= sc;
  float mx = fmaxf(fmaxf(s[0], s[1]), fmaxf(s[2], s[3]));
  mx = fmaxf(mx, __shfl_xor(mx, 1));
  mx = fmaxf(mx, __shfl_xor(mx, 2));
  mx = fmaxf(mx, __shfl_xor(mx, 4));
  mx = fmaxf(mx, __shfl_xor(mx, 8));
  f32x4 e;
  e[0] = __expf(s[0] - mx); e[1] = __expf(s[1] - mx);
  e[2] = __expf(s[2] - mx); e[3] = __expf(s[3] - mx);
  float sum = e[0] + e[1] + e[2] + e[3];
  sum += __shfl_xor(sum, 1);
  sum += __shfl_xor(sum, 2);
  sum += __shfl_xor(sum, 4);
  sum += __shfl_xor(sum, 8);
  float inv = 1.0f / sum;
  bf16x4 ov;
  ov[0] = (bf16)(e[0] * inv); ov[1] = (bf16)(e[1] * inv);
  ov[2] = (bf16)(e[2] * inv); ov[3] = (bf16)(e[3] * inv);
  *(bf16x4*)&attn[(size_t)p * 4096 + e0] = ov;
}

// ---------------- PV: o[s, n*64+h] = sum_k attn[h,k] * v[s,k] --------------------
__global__ __launch_bounds__(256) void k_pv(const bf16* __restrict__ qkv,
                                            const bf16* __restrict__ attn,
                                            bf16* __restrict__ o) {
  int blk = blockIdx.x;                  // p*16 + chunk
  int p = blk >> 4, ch = blk & 15;
  int b = p >> 4, n = p & 15;
  int t = threadIdx.x, lane = t & 63, w = t >> 6;
  int s0 = ch * 256 + w * 64;
  size_t vrow0 = (size_t)(b * 4096 + s0);
  const bf16* At = attn + (size_t)p * 4096;
  f32x4 acc[4][4] = {};
#pragma unroll
  for (int ks = 0; ks < 2; ++ks) {
    int kof = ks * 32 + ((lane >> 4) << 3);
    bf16x8 vf[4], af[4];
#pragma unroll
    for (int mi = 0; mi < 4; ++mi)
      vf[mi] = *(const bf16x8*)&qkv[(vrow0 + mi * 16 + (lane & 15)) * 3072 + 2048 + n * 64 + kof];
#pragma unroll
    for (int ni = 0; ni < 4; ++ni)
      af[ni] = *(const bf16x8*)&At[(size_t)(ni * 16 + (lane & 15)) * 64 + kof];
#pragma unroll
    for (int mi = 0; mi < 4; ++mi)
#pragma unroll
      for (int ni = 0; ni < 4; ++ni)
        acc[mi][ni] = __builtin_amdgcn_mfma_f32_16x16x32_bf16(vf[mi], af[ni], acc[mi][ni], 0, 0, 0);
  }
#pragma unroll
  for (int mi = 0; mi < 4; ++mi)
#pragma unroll
    for (int r = 0; r < 4; ++r) {
      int srow = s0 + mi * 16 + ((lane >> 4) << 2) + r;
      size_t base = ((size_t)(b * 4096 + srow)) * 1024 + n * 64 + (lane & 15);
#pragma unroll
      for (int ni = 0; ni < 4; ++ni)
        o[base + ni * 16] = (bf16)acc[mi][ni][r];
    }
}

// ---------------------------------------------------------------------------------
extern "C" void kernel_launch(void* const* d_in, const int* in_sizes, int n_in,
                              void* d_out, int out_size, void* d_ws, size_t ws_size,
                              hipStream_t stream) {
  const float* x    = (const float*)d_in[0];
  const float* gain = (const float*)d_in[1];
  const float* wq   = (const float*)d_in[2];
  const float* wk   = (const float*)d_in[3];
  const float* wv   = (const float*)d_in[4];
  const float* wo   = (const float*)d_in[5];

  char* ws = (char*)d_ws;
  bf16*  WN   = (bf16*)(ws + 0);
  bf16*  WNO  = (bf16*)(ws + 6291456);
  bf16*  xb   = (bf16*)(ws + 8388608);
  bf16*  qkv  = (bf16*)(ws + 41943040);
  float* part = (float*)(ws + 142606336);
  bf16*  attn = (bf16*)(ws + 209715200);
  bf16*  o    = xb;  // xb dead after gemm_qkv; reuse for o

  k_prep_w<<<4096, 256, 0, stream>>>(wq, wk, wv, wo, gain, WN, WNO);
  k_cvt_x<<<2048, 256, 0, stream>>>(x, xb);
  k_gemm<0><<<dim3(24, 128), 256, 0, stream>>>(xb, WN, (void*)qkv, nullptr, 3072);
  k_scores<<<4096, 256, 0, stream>>>(qkv, part);
  k_softmax<<<256, 256, 0, stream>>>(part, attn);
  k_pv<<<1024, 256, 0, stream>>>(qkv, attn, o);
  k_gemm<1><<<dim3(8, 128), 256, 0, stream>>>(o, WNO, d_out, x, 1024);
}

// Round 3
// 357.628 us; speedup vs baseline: 1.8134x; 1.1731x over previous
//
#include <hip/hip_runtime.h>
#include <math.h>

// MP_Attention: B=4,S=4096,E=1024,H=16,hd=64
// Pipeline: prep_w -> cvt_x -> gemm256_qkv(+qk head-norm epilogue) -> scores(partial)
//           -> softmax(reduce partials, parallel) -> pv -> gemm256_out(+residual mix)
// GEMM: 256x256 tile, BK=64, 8 waves, double-buffered 128KB LDS, 4-phase/K-tile
//       deep pipeline (T3/T4), XOR-swizzled LDS (T2, both-sides), setprio (T5),
//       bijective XCD swizzle (T1).
// Workspace layout (bytes):
//   WN   [3072x1024] bf16 @ 0          (6,291,456)
//   WNO  [1024x1024] bf16 @ 6291456    (2,097,152)
//   xb   [16384x1024] bf16 @ 8388608   (33,554,432)   (reused as `o` after gemm_qkv)
//   qkv  [16384x3072] bf16 @ 41943040  (100,663,296)
//   part [64][64][64][64] f32 @ 142606336 (67,108,864)
//   attn [64][64][64] bf16 @ 209715200 (524,288)

typedef __bf16 bf16;
typedef __bf16 bf16x8 __attribute__((ext_vector_type(8)));
typedef __bf16 bf16x4 __attribute__((ext_vector_type(4)));
typedef float  f32x4  __attribute__((ext_vector_type(4)));

#define DEVINL __device__ __forceinline__

DEVINL void gload_lds16(const void* g, void* l) {
  __builtin_amdgcn_global_load_lds(
      (__attribute__((address_space(1))) void*)(void*)g,
      (__attribute__((address_space(3))) void*)l, 16, 0, 0);
}

static constexpr int Sq = 4096;
static constexpr int Ek = 1024;
static constexpr int Mrows = 16384;   // B*S

// ---------------- weight prep: mp_normalize rows + gain/sqrt(fan_in), f32->bf16 ----
__global__ __launch_bounds__(256) void k_prep_w(
    const float* __restrict__ wq, const float* __restrict__ wk,
    const float* __restrict__ wv, const float* __restrict__ wo,
    const float* __restrict__ gain_p,
    bf16* __restrict__ WN, bf16* __restrict__ WNO) {
  int r = blockIdx.x;            // 0..4095
  int mat = r >> 10, row = r & 1023;
  const float* w = (mat == 0) ? wq : (mat == 1) ? wk : (mat == 2) ? wv : wo;
  int t = threadIdx.x;
  f32x4 v = *(const f32x4*)&w[(size_t)row * 1024 + t * 4];
  float ss = v[0]*v[0] + v[1]*v[1] + v[2]*v[2] + v[3]*v[3];
#pragma unroll
  for (int m2 = 1; m2 < 64; m2 <<= 1) ss += __shfl_xor(ss, m2);
  __shared__ float red[4];
  if ((t & 63) == 0) red[t >> 6] = ss;
  __syncthreads();
  float tot = red[0] + red[1] + red[2] + red[3];
  float g = gain_p[0];
  // wn = w / (eps + ||w||/32) * gain/32
  float scale = (g * 0.03125f) / (1e-4f + sqrtf(tot) * 0.03125f);
  bf16x4 ov;
  ov[0] = (bf16)(v[0]*scale); ov[1] = (bf16)(v[1]*scale);
  ov[2] = (bf16)(v[2]*scale); ov[3] = (bf16)(v[3]*scale);
  if (mat < 3) *(bf16x4*)&WN [(size_t)r   * 1024 + t * 4] = ov;
  else         *(bf16x4*)&WNO[(size_t)row * 1024 + t * 4] = ov;
}

// ---------------- x f32 -> bf16 -------------------------------------------------
__global__ __launch_bounds__(256) void k_cvt_x(const float* __restrict__ x,
                                               bf16* __restrict__ xb) {
  size_t idx = (size_t)blockIdx.x * 256 + threadIdx.x;
  const size_t n8 = (size_t)Mrows * Ek / 8;
  for (size_t i = idx; i < n8; i += (size_t)2048 * 256) {
    f32x4 a = *(const f32x4*)&x[i * 8];
    f32x4 b = *(const f32x4*)&x[i * 8 + 4];
    bf16x8 ov;
    ov[0]=(bf16)a[0]; ov[1]=(bf16)a[1]; ov[2]=(bf16)a[2]; ov[3]=(bf16)a[3];
    ov[4]=(bf16)b[0]; ov[5]=(bf16)b[1]; ov[6]=(bf16)b[2]; ov[7]=(bf16)b[3];
    *(bf16x8*)&xb[i * 8] = ov;
  }
}

// ---------------- 256x256 8-wave deep-pipelined GEMM -----------------------------
// C[M x N] = A[M x 1024] * Bw[N x 1024]^T
// EPI=0: store bf16, per-(row,64col head) mp_normalize for cols<2048 (q,k)
// EPI=1: store f32 = (resid + acc) * 1/sqrt(2)
// LDS tile: [256 rows][64 cols] bf16 per matrix, XOR-swizzled: element slot
// (8-elem granule) s stores global k-chunk s^(row&7). Staging pre-swizzles the
// GLOBAL source (rule #21); ds_read applies the XOR on the byte address.

DEVINL bf16x8 lds_frag(const bf16* base, int row, int kelem) {
  int byte = row * 128 + kelem * 2;
  byte ^= (row & 7) << 4;
  return *(const bf16x8*)((const char*)base + byte);
}

#define PH_BAR() do { __builtin_amdgcn_s_barrier();                    \
    asm volatile("s_waitcnt lgkmcnt(0)" ::: "memory");                 \
    __builtin_amdgcn_sched_barrier(0);                                 \
    __builtin_amdgcn_s_setprio(1); } while (0)
#define PH_END() do { __builtin_amdgcn_s_setprio(0);                   \
    __builtin_amdgcn_s_barrier(); } while (0)

template <int EPI>
__global__ __launch_bounds__(512, 2) void k_gemm256(
    const bf16* __restrict__ A, const bf16* __restrict__ Bw,
    void* __restrict__ Cout, const float* __restrict__ resid,
    int N, int NXB) {
  constexpr int K = 1024;
  constexpr int NT = K / 64;                 // 16 K-tiles
  __shared__ bf16 lds[2][2][256 * 64];       // [buf][A/B][tile] = 128 KiB

  // T1: bijective XCD swizzle (gridDim.x % 8 == 0 for both call sites)
  int nwg = gridDim.x;
  int bid = blockIdx.x;
  int cpx = nwg >> 3;
  int swz = (bid & 7) * cpx + (bid >> 3);
  int by = swz / NXB, bx = swz % NXB;
  int m0 = by * 256, n0 = bx * 256;

  int t = threadIdx.x;                       // 0..511
  int lane = t & 63, w = t >> 6;
  int wr = w >> 2, wc = w & 3;               // 2 x 4 wave grid
  int fr = lane & 15;
  int kof = (lane >> 4) * 8;                 // k element offset within k-half

  // staging: thread t covers LDS row srow (per 64-row chunk q), slot t&7.
  // Pre-swizzled global source slot:
  int srow = t >> 3;
  int sslot = (t & 7) ^ (srow & 7);
  const bf16* ag = A  + (size_t)(m0 + srow) * K + sslot * 8;
  const bf16* bg = Bw + (size_t)(n0 + srow) * K + sslot * 8;

  f32x4 acc[8][4] = {};

  int cur = 0;
  // prologue: stage K-tile 0 into buf0
  {
    bf16* An = &lds[0][0][0];
    bf16* Bn = &lds[0][1][0];
#pragma unroll
    for (int q = 0; q < 4; ++q)
      gload_lds16(ag + (size_t)q * 64 * K, &An[q * 4096 + t * 8]);
#pragma unroll
    for (int q = 0; q < 4; ++q)
      gload_lds16(bg + (size_t)q * 64 * K, &Bn[q * 4096 + t * 8]);
    asm volatile("s_waitcnt vmcnt(0)" ::: "memory");
    __builtin_amdgcn_s_barrier();
  }

  for (int kt = 0; kt < NT; ++kt) {
    const bf16* Ac = &lds[cur][0][0];
    const bf16* Bc = &lds[cur][1][0];
    bf16* An = &lds[cur ^ 1][0][0];
    bf16* Bn = &lds[cur ^ 1][1][0];
    bool pf = (kt + 1 < NT);
    int knext = (kt + 1) * 64;

    bf16x8 afr[4], bfr[4];

    // ---- phase 0: k-half 0, M-half 0; stage next A tile ----
#pragma unroll
    for (int i = 0; i < 4; ++i) bfr[i] = lds_frag(Bc, wc * 64 + i * 16 + fr, kof);
#pragma unroll
    for (int i = 0; i < 4; ++i) afr[i] = lds_frag(Ac, wr * 128 + i * 16 + fr, kof);
    if (pf) {
#pragma unroll
      for (int q = 0; q < 4; ++q)
        gload_lds16(ag + (size_t)q * 64 * K + knext, &An[q * 4096 + t * 8]);
    }
    PH_BAR();
#pragma unroll
    for (int mi = 0; mi < 4; ++mi)
#pragma unroll
      for (int ni = 0; ni < 4; ++ni)
        acc[mi][ni] = __builtin_amdgcn_mfma_f32_16x16x32_bf16(afr[mi], bfr[ni], acc[mi][ni], 0, 0, 0);
    PH_END();

    // ---- phase 1: k-half 0, M-half 1; stage next B tile ----
#pragma unroll
    for (int i = 0; i < 4; ++i) afr[i] = lds_frag(Ac, wr * 128 + (4 + i) * 16 + fr, kof);
    if (pf) {
#pragma unroll
      for (int q = 0; q < 4; ++q)
        gload_lds16(bg + (size_t)q * 64 * K + knext, &Bn[q * 4096 + t * 8]);
    }
    PH_BAR();
#pragma unroll
    for (int mi = 0; mi < 4; ++mi)
#pragma unroll
      for (int ni = 0; ni < 4; ++ni)
        acc[4 + mi][ni] = __builtin_amdgcn_mfma_f32_16x16x32_bf16(afr[mi], bfr[ni], acc[4 + mi][ni], 0, 0, 0);
    PH_END();

    // ---- phase 2: k-half 1, M-half 0 ----
#pragma unroll
    for (int i = 0; i < 4; ++i) bfr[i] = lds_frag(Bc, wc * 64 + i * 16 + fr, 32 + kof);
#pragma unroll
    for (int i = 0; i < 4; ++i) afr[i] = lds_frag(Ac, wr * 128 + i * 16 + fr, 32 + kof);
    PH_BAR();
#pragma unroll
    for (int mi = 0; mi < 4; ++mi)
#pragma unroll
      for (int ni = 0; ni < 4; ++ni)
        acc[mi][ni] = __builtin_amdgcn_mfma_f32_16x16x32_bf16(afr[mi], bfr[ni], acc[mi][ni], 0, 0, 0);
    PH_END();

    // ---- phase 3: k-half 1, M-half 1; tail: vmcnt drain + publish barrier ----
#pragma unroll
    for (int i = 0; i < 4; ++i) afr[i] = lds_frag(Ac, wr * 128 + (4 + i) * 16 + fr, 32 + kof);
    PH_BAR();
#pragma unroll
    for (int mi = 0; mi < 4; ++mi)
#pragma unroll
      for (int ni = 0; ni < 4; ++ni)
        acc[4 + mi][ni] = __builtin_amdgcn_mfma_f32_16x16x32_bf16(afr[mi], bfr[ni], acc[4 + mi][ni], 0, 0, 0);
    __builtin_amdgcn_s_setprio(0);
    asm volatile("s_waitcnt vmcnt(0)" ::: "memory");   // next tile's 8 loads landed
    __builtin_amdgcn_s_barrier();                      // publish buf[cur^1]; buf[cur] consumed
    cur ^= 1;
  }

  // ---- epilogue ----
  int colbase = n0 + wc * 64 + fr;
  if constexpr (EPI == 0) {
    bf16* C = (bf16*)Cout;
    bool dn = (n0 + wc * 64) < 2048;        // q,k heads get mp_normalize; v doesn't
#pragma unroll
    for (int mi = 0; mi < 8; ++mi) {
#pragma unroll
      for (int r = 0; r < 4; ++r) {
        float scale = 1.f;
        if (dn) {
          float ss = 0.f;
#pragma unroll
          for (int ni = 0; ni < 4; ++ni) { float v = acc[mi][ni][r]; ss += v * v; }
          ss += __shfl_xor(ss, 1); ss += __shfl_xor(ss, 2);
          ss += __shfl_xor(ss, 4); ss += __shfl_xor(ss, 8);
          scale = 1.f / (1e-4f + sqrtf(ss) * 0.125f);  // eps + ||v||/sqrt(64)
        }
        int row = m0 + wr * 128 + mi * 16 + ((lane >> 4) << 2) + r;
        size_t base = (size_t)row * N + colbase;
#pragma unroll
        for (int ni = 0; ni < 4; ++ni)
          C[base + ni * 16] = (bf16)(acc[mi][ni][r] * scale);
      }
    }
  } else {
    float* C = (float*)Cout;
#pragma unroll
    for (int mi = 0; mi < 8; ++mi) {
#pragma unroll
      for (int r = 0; r < 4; ++r) {
        int row = m0 + wr * 128 + mi * 16 + ((lane >> 4) << 2) + r;
        size_t base = (size_t)row * N + colbase;
#pragma unroll
        for (int ni = 0; ni < 4; ++ni) {
          size_t idx = base + ni * 16;
          C[idx] = (resid[idx] + acc[mi][ni][r]) * 0.70710678118654752f;
        }
      }
    }
  }
}

// ---------------- scores partials: part[p][c][h][k] = sum_{s in chunk} qn*kn -----
__global__ __launch_bounds__(256) void k_scores(const bf16* __restrict__ qkv,
                                                float* __restrict__ part) {
  __shared__ float Qs[64][64];
  __shared__ float Ks[64][64];
  int blk = blockIdx.x;                  // p*64 + c
  int p = blk >> 6, c = blk & 63;
  int b = p >> 4, n = p & 15;
  int t = threadIdx.x;
  int j = t & 7;
  size_t rowbase = ((size_t)(b * 4096 + c * 64)) * 3072 + n * 64 + j * 8;
#pragma unroll
  for (int i = 0; i < 2; ++i) {
    int sl = i * 32 + (t >> 3);
    bf16x8 qv = *(const bf16x8*)&qkv[rowbase + (size_t)sl * 3072];
    bf16x8 kv = *(const bf16x8*)&qkv[rowbase + (size_t)sl * 3072 + 1024];
    f32x4 q0, q1, k0v, k1v;
    q0[0]=(float)qv[0]; q0[1]=(float)qv[1]; q0[2]=(float)qv[2]; q0[3]=(float)qv[3];
    q1[0]=(float)qv[4]; q1[1]=(float)qv[5]; q1[2]=(float)qv[6]; q1[3]=(float)qv[7];
    k0v[0]=(float)kv[0]; k0v[1]=(float)kv[1]; k0v[2]=(float)kv[2]; k0v[3]=(float)kv[3];
    k1v[0]=(float)kv[4]; k1v[1]=(float)kv[5]; k1v[2]=(float)kv[6]; k1v[3]=(float)kv[7];
    *(f32x4*)&Qs[sl][j * 8]     = q0;
    *(f32x4*)&Qs[sl][j * 8 + 4] = q1;
    *(f32x4*)&Ks[sl][j * 8]     = k0v;
    *(f32x4*)&Ks[sl][j * 8 + 4] = k1v;
  }
  __syncthreads();
  int h0 = (t >> 4) << 2, k0 = (t & 15) << 2;
  float acc[4][4] = {};
  for (int s = 0; s < 64; ++s) {
    f32x4 q  = *(const f32x4*)&Qs[s][h0];
    f32x4 kk = *(const f32x4*)&Ks[s][k0];
#pragma unroll
    for (int a = 0; a < 4; ++a) {
      acc[a][0] += q[a] * kk[0]; acc[a][1] += q[a] * kk[1];
      acc[a][2] += q[a] * kk[2]; acc[a][3] += q[a] * kk[3];
    }
  }
  size_t base = (size_t)blk * 4096;
#pragma unroll
  for (int a = 0; a < 4; ++a) {
    f32x4 st; st[0]=acc[a][0]; st[1]=acc[a][1]; st[2]=acc[a][2]; st[3]=acc[a][3];
    *(f32x4*)&part[base + (size_t)(h0 + a) * 64 + k0] = st;
  }
}

// ---------------- reduce partials + softmax over k (64), parallel ----------------
__global__ __launch_bounds__(256) void k_softmax(const float* __restrict__ part,
                                                 bf16* __restrict__ attn) {
  int blk = blockIdx.x;                  // p*4 + q
  int p = blk >> 2, q = blk & 3;
  int t = threadIdx.x;
  int e0 = q * 1024 + t * 4;
  const float* pp = part + (size_t)p * 64 * 4096 + e0;
  f32x4 s = {};
#pragma unroll 4
  for (int c = 0; c < 64; ++c) {
    f32x4 v = *(const f32x4*)&pp[(size_t)c * 4096];
    s[0] += v[0]; s[1] += v[1]; s[2] += v[2]; s[3] += v[3];
  }
  const float sc = 1.0f / 64.0f;         // 1/sqrt(S)
  s[0] *= sc; s[1] *= sc; s[2] *= sc; s[3] *= sc;
  float mx = fmaxf(fmaxf(s[0], s[1]), fmaxf(s[2], s[3]));
  mx = fmaxf(mx, __shfl_xor(mx, 1));
  mx = fmaxf(mx, __shfl_xor(mx, 2));
  mx = fmaxf(mx, __shfl_xor(mx, 4));
  mx = fmaxf(mx, __shfl_xor(mx, 8));
  f32x4 e;
  e[0] = __expf(s[0] - mx); e[1] = __expf(s[1] - mx);
  e[2] = __expf(s[2] - mx); e[3] = __expf(s[3] - mx);
  float sum = e[0] + e[1] + e[2] + e[3];
  sum += __shfl_xor(sum, 1);
  sum += __shfl_xor(sum, 2);
  sum += __shfl_xor(sum, 4);
  sum += __shfl_xor(sum, 8);
  float inv = 1.0f / sum;
  bf16x4 ov;
  ov[0] = (bf16)(e[0] * inv); ov[1] = (bf16)(e[1] * inv);
  ov[2] = (bf16)(e[2] * inv); ov[3] = (bf16)(e[3] * inv);
  *(bf16x4*)&attn[(size_t)p * 4096 + e0] = ov;
}

// ---------------- PV: o[s, n*64+h] = sum_k attn[h,k] * v[s,k] --------------------
__global__ __launch_bounds__(256) void k_pv(const bf16* __restrict__ qkv,
                                            const bf16* __restrict__ attn,
                                            bf16* __restrict__ o) {
  int blk = blockIdx.x;                  // p*16 + chunk
  int p = blk >> 4, ch = blk & 15;
  int b = p >> 4, n = p & 15;
  int t = threadIdx.x, lane = t & 63, w = t >> 6;
  int s0 = ch * 256 + w * 64;
  size_t vrow0 = (size_t)(b * 4096 + s0);
  const bf16* At = attn + (size_t)p * 4096;
  f32x4 acc[4][4] = {};
#pragma unroll
  for (int ks = 0; ks < 2; ++ks) {
    int kof = ks * 32 + ((lane >> 4) << 3);
    bf16x8 vf[4], af[4];
#pragma unroll
    for (int mi = 0; mi < 4; ++mi)
      vf[mi] = *(const bf16x8*)&qkv[(vrow0 + mi * 16 + (lane & 15)) * 3072 + 2048 + n * 64 + kof];
#pragma unroll
    for (int ni = 0; ni < 4; ++ni)
      af[ni] = *(const bf16x8*)&At[(size_t)(ni * 16 + (lane & 15)) * 64 + kof];
#pragma unroll
    for (int mi = 0; mi < 4; ++mi)
#pragma unroll
      for (int ni = 0; ni < 4; ++ni)
        acc[mi][ni] = __builtin_amdgcn_mfma_f32_16x16x32_bf16(vf[mi], af[ni], acc[mi][ni], 0, 0, 0);
  }
#pragma unroll
  for (int mi = 0; mi < 4; ++mi)
#pragma unroll
    for (int r = 0; r < 4; ++r) {
      int srow = s0 + mi * 16 + ((lane >> 4) << 2) + r;
      size_t base = ((size_t)(b * 4096 + srow)) * 1024 + n * 64 + (lane & 15);
#pragma unroll
      for (int ni = 0; ni < 4; ++ni)
        o[base + ni * 16] = (bf16)acc[mi][ni][r];
    }
}

// ---------------------------------------------------------------------------------
extern "C" void kernel_launch(void* const* d_in, const int* in_sizes, int n_in,
                              void* d_out, int out_size, void* d_ws, size_t ws_size,
                              hipStream_t stream) {
  const float* x    = (const float*)d_in[0];
  const float* gain = (const float*)d_in[1];
  const float* wq   = (const float*)d_in[2];
  const float* wk   = (const float*)d_in[3];
  const float* wv   = (const float*)d_in[4];
  const float* wo   = (const float*)d_in[5];

  char* ws = (char*)d_ws;
  bf16*  WN   = (bf16*)(ws + 0);
  bf16*  WNO  = (bf16*)(ws + 6291456);
  bf16*  xb   = (bf16*)(ws + 8388608);
  bf16*  qkv  = (bf16*)(ws + 41943040);
  float* part = (float*)(ws + 142606336);
  bf16*  attn = (bf16*)(ws + 209715200);
  bf16*  o    = xb;  // xb dead after gemm_qkv; reuse for o

  k_prep_w<<<4096, 256, 0, stream>>>(wq, wk, wv, wo, gain, WN, WNO);
  k_cvt_x<<<2048, 256, 0, stream>>>(x, xb);
  // QKV: M=16384, N=3072 -> 64 x 12 = 768 blocks (768 % 8 == 0)
  k_gemm256<0><<<768, 512, 0, stream>>>(xb, WN, (void*)qkv, nullptr, 3072, 12);
  k_scores<<<4096, 256, 0, stream>>>(qkv, part);
  k_softmax<<<256, 256, 0, stream>>>(part, attn);
  k_pv<<<1024, 256, 0, stream>>>(qkv, attn, o);
  // OUT: M=16384, N=1024 -> 64 x 4 = 256 blocks (256 % 8 == 0)
  k_gemm256<1><<<256, 512, 0, stream>>>(o, WNO, d_out, x, 1024, 4);
}